// Round 8
// baseline (67.564 us; speedup 1.0000x reference)
//
#include <hip/hip_runtime.h>
#include <hip/hip_bf16.h>

// y = softmax_causal((x Wq^T)(x Wk^T)^T / 8) (x Wv^T)
// B=4, S=4096, D_EMBED=1024, D=64. fp32 in/out; bf16 MFMA compute.

typedef short s16x8 __attribute__((ext_vector_type(8)));
typedef float f32x4 __attribute__((ext_vector_type(4)));
typedef float f32x16 __attribute__((ext_vector_type(16)));
typedef unsigned u32x2 __attribute__((ext_vector_type(2)));

#define MFMA16(a, b, c) __builtin_amdgcn_mfma_f32_16x16x32_bf16(a, b, c, 0, 0, 0)
#define MFMA32(a, b, c) __builtin_amdgcn_mfma_f32_32x32x16_bf16(a, b, c, 0, 0, 0)

constexpr int SEQ = 4096;
constexpr int DE  = 1024;

__device__ __forceinline__ short f2bf(float f) {            // RNE fp32->bf16
    union { float f; unsigned u; } v; v.f = f;
    unsigned r = (v.u + 0x7FFFu + ((v.u >> 16) & 1u)) >> 16;
    return (short)r;
}
__device__ __forceinline__ unsigned fbits(float f) { union { float f; unsigned u; } v; v.f = f; return v.u; }
__device__ __forceinline__ float bitsf(unsigned u) { union { unsigned u; float f; } v; v.u = u; return v.f; }
__device__ __forceinline__ unsigned pk2(float a, float b) {  // 2xf32 -> packed bf16 (trunc)
    return (fbits(b) & 0xFFFF0000u) | (fbits(a) >> 16);
}

#define GLDS(gp, lp)                                                          \
    __builtin_amdgcn_global_load_lds(                                         \
        (const __attribute__((address_space(1))) unsigned int*)(gp),          \
        (__attribute__((address_space(3))) unsigned int*)(lp), 16, 0, 0)

// ---------------------------------------------------------------------------
// Kernel 0: W (fp32 [64][1024] x3) -> bf16 [192][1024]; 0.125*log2e folded in Wq.
__global__ __launch_bounds__(256) void k_convw(const float* __restrict__ Wq,
                                               const float* __restrict__ Wk,
                                               const float* __restrict__ Wv,
                                               short* __restrict__ Wb) {
    int i = (blockIdx.x * 256 + threadIdx.x) * 4;
    if (i >= 192 * 1024) return;
    int n = i >> 10, k = i & 1023;
    const float* src; float sc;
    if (n < 64)       { src = Wq + n * 1024;         sc = 0.18033688011112042f; }
    else if (n < 128) { src = Wk + (n - 64) * 1024;  sc = 1.0f; }
    else              { src = Wv + (n - 128) * 1024; sc = 1.0f; }
    float4 v = *(const float4*)(src + k);
    short4 o;
    o.x = f2bf(v.x * sc); o.y = f2bf(v.y * sc);
    o.z = f2bf(v.z * sc); o.w = f2bf(v.w * sc);
    *(short4*)(Wb + i) = o;
}

// ---------------------------------------------------------------------------
// Kernel 1: QKV projection (R5 version, known ~26us): BM=64, BN=192, BK=64,
// 8 waves, counted vmcnt(5), 256 blocks x 512 thr.
__global__ __launch_bounds__(512) void k_proj(const float* __restrict__ x,
                                              const short* __restrict__ Wb,
                                              short* __restrict__ Qs,
                                              short* __restrict__ Ks,
                                              short* __restrict__ Vt) {
    __shared__ __align__(16) char lds[2][40960];   // per buf: A 16KB | W 24KB
    const int tid  = threadIdx.x;
    const int lane = tid & 63;
    const int c = lane & 15, g = (lane >> 4) & 3;
    const int wv = tid >> 6;
    const int rg = wv & 3, nh = wv >> 2;
    const int n0 = nh * 96;
    const int m0 = blockIdx.x * 64;

    const int Ar  = tid >> 4;
    const int Acs = ((tid & 15) << 4) ^ ((Ar & 7) << 4);
    const char* aS0 = (const char*)x + (((size_t)(m0 + Ar)) << 12) + Acs;
    const char* aS1 = aS0 + ((size_t)32 << 12);
    const int Wr  = tid >> 3;
    const int Wcs = ((tid & 7) << 4) ^ ((Wr & 7) << 4);
    const char* wS0 = (const char*)Wb + (((size_t)Wr) << 11) + Wcs;
    const char* wS1 = wS0 + ((size_t)64 << 11);
    const char* wS2 = wS0 + ((size_t)128 << 11);

    char* db0 = &lds[0][0] + tid * 16;
    char* db1 = &lds[1][0] + tid * 16;

    const int arow = rg * 16 + c;
    const int swz  = (c & 7) << 4;
    const char* aR[2] = { &lds[0][0] + arow * 256, &lds[1][0] + arow * 256 };
    const char* wR[2][6];
#pragma unroll
    for (int nf = 0; nf < 6; nf++) {
        int wrow = n0 + nf * 16 + c;
        wR[0][nf] = &lds[0][0] + 16384 + wrow * 128;
        wR[1][nf] = &lds[1][0] + 16384 + wrow * 128;
    }

    f32x4 acc[6];
#pragma unroll
    for (int i = 0; i < 6; i++) acc[i] = (f32x4){0.f, 0.f, 0.f, 0.f};

#define PSTAGE(kk, db) {                                  \
        GLDS(aS0 + (kk) * 256, (db));                     \
        GLDS(aS1 + (kk) * 256, (db) + 8192);              \
        GLDS(wS0 + (kk) * 128, (db) + 16384);             \
        GLDS(wS1 + (kk) * 128, (db) + 24576);             \
        GLDS(wS2 + (kk) * 128, (db) + 32768); }

#define PCOMPUTE(bi) {                                                         \
        _Pragma("unroll")                                                      \
        for (int kc = 0; kc < 2; kc++) {                                       \
            float4 a0 = *(const float4*)(aR[bi] + ((kc*128 + g*32)      ^ swz)); \
            float4 a1 = *(const float4*)(aR[bi] + ((kc*128 + g*32 + 16) ^ swz)); \
            s16x8 a;                                                           \
            a[0]=f2bf(a0.x); a[1]=f2bf(a0.y); a[2]=f2bf(a0.z); a[3]=f2bf(a0.w); \
            a[4]=f2bf(a1.x); a[5]=f2bf(a1.y); a[6]=f2bf(a1.z); a[7]=f2bf(a1.w); \
            _Pragma("unroll")                                                  \
            for (int nf = 0; nf < 6; nf++) {                                   \
                s16x8 bfr = *(const s16x8*)(wR[bi][nf] + ((kc*64 + g*16) ^ swz)); \
                acc[nf] = MFMA16(a, bfr, acc[nf]);                             \
            }                                                                  \
        } }

    PSTAGE(0, db0);
    PSTAGE(1, db1);

    for (int kk = 0; kk < 15; kk++) {
        asm volatile("s_waitcnt vmcnt(5)" ::: "memory");
        __builtin_amdgcn_sched_barrier(0);
        __builtin_amdgcn_s_barrier();
        if (kk & 1) PCOMPUTE(1) else PCOMPUTE(0)
        asm volatile("s_waitcnt lgkmcnt(0)" ::: "memory");
        __builtin_amdgcn_sched_barrier(0);
        __builtin_amdgcn_s_barrier();
        if (kk < 14) { if (kk & 1) PSTAGE(kk + 2, db1) else PSTAGE(kk + 2, db0) }
    }
    asm volatile("s_waitcnt vmcnt(0)" ::: "memory");
    __builtin_amdgcn_sched_barrier(0);
    __builtin_amdgcn_s_barrier();
    PCOMPUTE(1)
#undef PSTAGE
#undef PCOMPUTE

#pragma unroll
    for (int nf = 0; nf < 6; nf++) {
        int col16 = n0 + nf * 16;
        if (col16 < 64) {
            int col = col16 + c;
#pragma unroll
            for (int r = 0; r < 4; r++)
                Qs[(size_t)(m0 + rg * 16 + g * 4 + r) * 64 + col] = f2bf(acc[nf][r]);
        } else if (col16 < 128) {
            int col = col16 - 64 + c;
#pragma unroll
            for (int r = 0; r < 4; r++)
                Ks[(size_t)(m0 + rg * 16 + g * 4 + r) * 64 + col] = f2bf(acc[nf][r]);
        } else {
            int d  = col16 - 128 + c;
            int mm = m0 + rg * 16 + g * 4;
            int bt = mm >> 12, s0 = mm & (SEQ - 1);
            short4 o;
            o.x = f2bf(acc[nf][0]); o.y = f2bf(acc[nf][1]);
            o.z = f2bf(acc[nf][2]); o.w = f2bf(acc[nf][3]);
            *(short4*)(Vt + ((size_t)(bt * 64 + d)) * SEQ + s0) = o;
        }
    }
}

// ---------------------------------------------------------------------------
// Kernel 2 (v3): flash attention with K/V amortized over 128 q-rows/block.
// Block = 4 waves; wave w owns q-rows [j*128+w*32, +32). Per 64-kv round the
// block stages K (8KB) + V (8KB) slabs once (dbuf, vmcnt(4), XOR swizzle) and
// ALL waves consume them -> K/V L2 traffic /4 vs q32 tiling. Work unit =
// (bt, 128q-tile j, 512-kv segment): 576 blocks, <=8 rounds, heavy-first.
// Per-wave partial (O^T, M, L) -> ws; k_comb merges <=8 segments.
__global__ __launch_bounds__(256, 3) void k_attn(const short* __restrict__ Qs,
                                                 const short* __restrict__ Ks,
                                                 const short* __restrict__ Vt,
                                                 float* __restrict__ pws) {
    __shared__ __align__(16) char smem[2][16384];   // per buf: K 8KB | V 8KB

    int tid = threadIdx.x;
    int l = tid & 63, wv = tid >> 6;
    int q = l & 31, hi = l >> 5;

    // decode unit: heavy tiles (large j) first; nseg(j) = ceil((j+1)/4)
    int ub = blockIdx.x >> 2, bt = blockIdx.x & 3;
    int u = ub, j = 31, cs = 8;
    while (u >= cs) { u -= cs; --j; cs = (j + 4) >> 2; }
    int seg = u;
    int kb0 = seg << 9;
    int kend_t = min(j * 128 + 128, kb0 + 512);
    const int R = (kend_t - kb0 + 63) >> 6;
    int q0 = j * 128 + wv * 32;              // this wave's q-tile
    int mycend = q0 + 32;                    // causal end for this wave

    const short* Qb = Qs + (size_t)bt * SEQ * 64;
    const short* Kb = Ks + (size_t)bt * SEQ * 64;
    const short* Vb = Vt + (size_t)bt * 64 * SEQ;

    s16x8 qf[4];
#pragma unroll
    for (int d = 0; d < 4; d++)
        qf[d] = *(const s16x8*)(Qb + (size_t)(q0 + q) * 64 + d * 16 + hi * 8);

    // staging constants: thread covers row (l>>3), chunk (l&7); source chunk
    // pre-XORed so LDS[row][c] = src[row][c ^ (row&7)]
    const int row8 = l >> 3;
    const int scs  = (l & 7) ^ row8;

#define ASTAGE(kb, b) {                                                        \
        _Pragma("unroll")                                                      \
        for (int i = 0; i < 2; i++) {                                          \
            GLDS(Kb + (((size_t)((kb) + wv*16 + i*8 + row8)) << 6) + scs*8,    \
                 &smem[b][0] + (wv*16 + i*8)*128);                             \
            GLDS(Vb + (size_t)(wv*16 + i*8 + row8) * SEQ + (kb) + scs*8,       \
                 &smem[b][0] + 8192 + (wv*16 + i*8)*128); } }

    f32x16 o0 = {}, o1 = {};
    float m = -1e30f, ll = 0.f;
    const int qs7 = q & 7;

    ASTAGE(kb0, 0);
    if (R > 1) ASTAGE(kb0 + 64, 1);

    for (int r = 0; r < R; r++) {
        if (r == R - 1) asm volatile("s_waitcnt vmcnt(0)" ::: "memory");
        else            asm volatile("s_waitcnt vmcnt(4)" ::: "memory");
        __builtin_amdgcn_sched_barrier(0);
        __builtin_amdgcn_s_barrier();
        __builtin_amdgcn_sched_barrier(0);

        int k0 = kb0 + r * 64;
        if (k0 < mycend) {
            const char* kl = &smem[r & 1][0];
            // ---- S^T = K Q^T for two 32-kv subtiles ----
            f32x16 sa = {}, sb = {};
#pragma unroll
            for (int dd = 0; dd < 4; dd++) {
                int ch = ((2 * dd + hi) ^ qs7) << 4;
                s16x8 ka = *(const s16x8*)(kl + q * 128 + ch);
                s16x8 kb2 = *(const s16x8*)(kl + (32 + q) * 128 + ch);
                sa = MFMA32(ka,  qf[dd], sa);
                sb = MFMA32(kb2, qf[dd], sb);
            }
            // ---- causal mask ----
            if (k0 + 31 > q0) {
#pragma unroll
                for (int rr = 0; rr < 16; rr++) {
                    int kv = k0 + (rr & 3) + 8 * (rr >> 2) + 4 * hi;
                    if (kv > q0 + q) sa[rr] = -3.0e38f;
                }
            }
            if (k0 + 63 > q0) {
#pragma unroll
                for (int rr = 0; rr < 16; rr++) {
                    int kv = k0 + 32 + (rr & 3) + 8 * (rr >> 2) + 4 * hi;
                    if (kv > q0 + q) sb[rr] = -3.0e38f;
                }
            }
            // ---- in-register softmax (base-2, scale folded in Wq) ----
            float t0 = -3.0e38f, t1 = -3.0e38f;
#pragma unroll
            for (int rr = 0; rr < 16; rr++) { t0 = fmaxf(t0, sa[rr]); t1 = fmaxf(t1, sb[rr]); }
            float tm = fmaxf(t0, t1);
            u32x2 sw = __builtin_amdgcn_permlane32_swap(fbits(tm), fbits(tm), false, false);
            tm = fmaxf(bitsf(sw[0]), bitsf(sw[1]));
            float mn = fmaxf(m, tm);
            float scale = __builtin_amdgcn_exp2f(m - mn);
            m = mn;
            float ss = 0.f;
#pragma unroll
            for (int rr = 0; rr < 16; rr++) {
                sa[rr] = __builtin_amdgcn_exp2f(sa[rr] - mn);
                sb[rr] = __builtin_amdgcn_exp2f(sb[rr] - mn);
                ss += sa[rr] + sb[rr];
            }
            sw = __builtin_amdgcn_permlane32_swap(fbits(ss), fbits(ss), false, false);
            ss = bitsf(sw[0]) + bitsf(sw[1]);
            ll = ll * scale + ss;
            o0 *= scale; o1 *= scale;

            // ---- P -> bf16 B-frags (kv 0-15,16-31,32-47,48-63) ----
            union { unsigned u[4]; s16x8 v; } pA0, pA1, pB0, pB1;
            {
                unsigned A0 = pk2(sa[0], sa[1]),   B0 = pk2(sa[2], sa[3]);
                unsigned A1 = pk2(sa[4], sa[5]),   B1 = pk2(sa[6], sa[7]);
                unsigned A2 = pk2(sa[8], sa[9]),   B2 = pk2(sa[10], sa[11]);
                unsigned A3 = pk2(sa[12], sa[13]), B3 = pk2(sa[14], sa[15]);
                u32x2 r0 = __builtin_amdgcn_permlane32_swap(A0, A1, false, false);
                u32x2 r1 = __builtin_amdgcn_permlane32_swap(B0, B1, false, false);
                u32x2 r2 = __builtin_amdgcn_permlane32_swap(A2, A3, false, false);
                u32x2 r3 = __builtin_amdgcn_permlane32_swap(B2, B3, false, false);
                pA0.u[0] = r0[0]; pA0.u[1] = r1[0]; pA0.u[2] = r0[1]; pA0.u[3] = r1[1];
                pA1.u[0] = r2[0]; pA1.u[1] = r3[0]; pA1.u[2] = r2[1]; pA1.u[3] = r3[1];
            }
            {
                unsigned A0 = pk2(sb[0], sb[1]),   B0 = pk2(sb[2], sb[3]);
                unsigned A1 = pk2(sb[4], sb[5]),   B1 = pk2(sb[6], sb[7]);
                unsigned A2 = pk2(sb[8], sb[9]),   B2 = pk2(sb[10], sb[11]);
                unsigned A3 = pk2(sb[12], sb[13]), B3 = pk2(sb[14], sb[15]);
                u32x2 r0 = __builtin_amdgcn_permlane32_swap(A0, A1, false, false);
                u32x2 r1 = __builtin_amdgcn_permlane32_swap(B0, B1, false, false);
                u32x2 r2 = __builtin_amdgcn_permlane32_swap(A2, A3, false, false);
                u32x2 r3 = __builtin_amdgcn_permlane32_swap(B2, B3, false, false);
                pB0.u[0] = r0[0]; pB0.u[1] = r1[0]; pB0.u[2] = r0[1]; pB0.u[3] = r1[1];
                pB1.u[0] = r2[0]; pB1.u[1] = r3[0]; pB1.u[2] = r2[1]; pB1.u[3] = r3[1];
            }

            // ---- O^T += V^T P^T over 64 kv ----
            const char* vl = &smem[r & 1][0] + 8192;
            const char* v0p = vl + q * 128;
            const char* v1p = vl + (32 + q) * 128;
            int c0 = ((0 + hi) ^ qs7) << 4, c1 = ((2 + hi) ^ qs7) << 4;
            int c2 = ((4 + hi) ^ qs7) << 4, c3 = ((6 + hi) ^ qs7) << 4;
            o0 = MFMA32(*(const s16x8*)(v0p + c0), pA0.v, o0);
            o0 = MFMA32(*(const s16x8*)(v0p + c1), pA1.v, o0);
            o0 = MFMA32(*(const s16x8*)(v0p + c2), pB0.v, o0);
            o0 = MFMA32(*(const s16x8*)(v0p + c3), pB1.v, o0);
            o1 = MFMA32(*(const s16x8*)(v1p + c0), pA0.v, o1);
            o1 = MFMA32(*(const s16x8*)(v1p + c1), pA1.v, o1);
            o1 = MFMA32(*(const s16x8*)(v1p + c2), pB0.v, o1);
            o1 = MFMA32(*(const s16x8*)(v1p + c3), pB1.v, o1);
        }

        asm volatile("s_waitcnt lgkmcnt(0)" ::: "memory");
        __builtin_amdgcn_sched_barrier(0);
        __builtin_amdgcn_s_barrier();
        if (r + 2 < R) { if (r & 1) ASTAGE(kb0 + (r + 2) * 64, 1) else ASTAGE(kb0 + (r + 2) * 64, 0) }
    }
#undef ASTAGE

    // ---- per-wave partial -> ws (no cross-wave combine needed) ----
    float* p = pws + ((size_t)blockIdx.x * 4 + wv) * 2112;
#pragma unroll
    for (int rr = 0; rr < 16; rr++) {
        int dv = (rr & 3) + 8 * (rr >> 2) + 4 * hi;
        p[dv * 32 + q]        = o0[rr];
        p[(dv + 32) * 32 + q] = o1[rr];
    }
    if (hi == 0) { p[2048 + q] = m; p[2080 + q] = ll; }
}

// ---------------------------------------------------------------------------
// Kernel 3: merge <=8 segment partials per (bt, j, wave-sub) -> fp32 out.
__global__ __launch_bounds__(256) void k_comb(const float* __restrict__ pws,
                                              float* __restrict__ out) {
    int b = blockIdx.x;                      // w*128 + j*4 + bt
    int bt = b & 3, j = (b >> 2) & 31, w = b >> 7;
    int nseg = (j + 4) >> 2;
    int ubb = 0;
    for (int jj = 31; jj > j; --jj) ubb += (jj + 4) >> 2;

    int tid = threadIdx.x;
    int q = tid >> 3, dv0 = (tid & 7) * 8;

    const float* rec[8];
    float ms[8];
    float M = -1e30f;
#pragma unroll
    for (int s = 0; s < 8; s++) {
        if (s < nseg) {
            rec[s] = pws + ((size_t)(((ubb + s) * 4 + bt) * 4 + w)) * 2112;
            ms[s] = rec[s][2048 + q];
            M = fmaxf(M, ms[s]);
        }
    }
    float L = 0.f, wsg[8];
#pragma unroll
    for (int s = 0; s < 8; s++) {
        if (s < nseg) {
            wsg[s] = __builtin_amdgcn_exp2f(ms[s] - M);
            L += wsg[s] * rec[s][2080 + q];
        }
    }
    float inv = 1.0f / L;
    float res[8];
#pragma unroll
    for (int i = 0; i < 8; i++) res[i] = 0.f;
#pragma unroll
    for (int s = 0; s < 8; s++) {
        if (s < nseg) {
#pragma unroll
            for (int i = 0; i < 8; i++)
                res[i] += wsg[s] * rec[s][(dv0 + i) * 32 + q];
        }
    }
    int qout = j * 128 + w * 32 + q;
    float* op = out + ((size_t)bt * SEQ + qout) * 64 + dv0;
    float4 f0 = {res[0] * inv, res[1] * inv, res[2] * inv, res[3] * inv};
    float4 f1 = {res[4] * inv, res[5] * inv, res[6] * inv, res[7] * inv};
    *(float4*)op = f0;
    *(float4*)(op + 4) = f1;
}

// ---------------------------------------------------------------------------
extern "C" void kernel_launch(void* const* d_in, const int* in_sizes, int n_in,
                              void* d_out, int out_size, void* d_ws, size_t ws_size,
                              hipStream_t stream) {
    const float* x  = (const float*)d_in[0];
    const float* Wq = (const float*)d_in[1];
    const float* Wk = (const float*)d_in[2];
    const float* Wv = (const float*)d_in[3];
    float* out = (float*)d_out;

    char* ws = (char*)d_ws;
    short* Wb = (short*)ws;                                   // 384 KB
    short* Qs = (short*)(ws + 393216);                        // 2 MB
    short* Ks = (short*)(ws + 393216 + 2097152);              // 2 MB
    short* Vt = (short*)(ws + 393216 + 2 * 2097152);          // 2 MB  [B][64][S]
    float* pP = (float*)(ws + 6684672);                       // partials ~19.5 MB

    k_convw<<<dim3(192), dim3(256), 0, stream>>>(Wq, Wk, Wv, Wb);
    k_proj <<<dim3(256), dim3(512), 0, stream>>>(x, Wb, Qs, Ks, Vt);
    k_attn <<<dim3(576), dim3(256), 0, stream>>>(Qs, Ks, Vt, pP);
    k_comb <<<dim3(512), dim3(256), 0, stream>>>(pP, out);
}